// Round 3
// baseline (1076.150 us; speedup 1.0000x reference)
//
#include <hip/hip_runtime.h>
#include <math.h>

namespace {
constexpr int SEQ   = 512;
constexpr int VOCAB = 128;
constexpr int EMBED = 128;
constexpr int HID   = 256;
constexpr int NSTEP = 511;   // SEQ-1 outputs
constexpr int BLK   = 512;   // 8 waves
constexpr int NROW  = 2;     // batch rows per block
constexpr int NBLK  = 256;   // 512/NROW = 1 block per CU
}

// P[v][j] = dot(emb[v,:], Wxh[j,:]).  Static device buffer: graph-capture-safe,
// rewritten identically every launch (no call-count dependence).
__device__ float g_P[VOCAB * HID];

__global__ void precompute_P(const float* __restrict__ emb,
                             const float* __restrict__ Wxh)
{
    __shared__ __align__(16) float es[EMBED];
    const int v = blockIdx.x;      // 128 blocks
    const int j = threadIdx.x;     // 256 threads -> one output j each
    if (j < EMBED) es[j] = emb[(size_t)v * EMBED + j];
    __syncthreads();
    const float4* w4 = (const float4*)(Wxh + (size_t)j * EMBED);
    const float4* e4 = (const float4*)es;
    float a = 0.f;
    #pragma unroll
    for (int k = 0; k < EMBED / 4; ++k) {
        float4 w = w4[k], e = e4[k];
        a += w.x * e.x + w.y * e.y + w.z * e.z + w.w * e.w;
    }
    g_P[v * HID + j] = a;
}

// float4-chunk swizzle (involution): c -> c ^ ((c>>3)&7).
// Guarantees: reads of chunk set {g*8 + (i^g)} have distinct bank-groups i^g.
__device__ __forceinline__ int swz_c(int c) { return c ^ ((c >> 3) & 7); }

// WSTAG only encodes ws_size bracket into the dispatch name (rocprof probe).
template<int WSTAG>
__global__ __launch_bounds__(BLK, 2)
void rnn_fused3(const int* __restrict__ x,   const float* __restrict__ Whh,
                const float* __restrict__ bhh, const float* __restrict__ bxh,
                const float* __restrict__ Why, const float* __restrict__ bhy,
                const float* __restrict__ h0,  float* __restrict__ out)
{
    // h double-buffer only: [2 parity][2 row][256 floats], swizzled chunks
    __shared__ __align__(16) float h_s[2 * NROW * HID];

    const int tid = threadIdx.x;
    const int r0  = blockIdx.x * NROW;

    const int lk  = tid & 7;          // k-slice owner: k in [lk*32, lk*32+32)
    const int jg  = tid >> 3;         // 0..63
    const int jsel = (jg << 2) | (tid & 3);       // owned hidden unit (dup x2 via tid&4)
    const int rsel = (tid & 4) ? 1 : 0;           // which batch row this lane stores
    const int v0  = jg << 1;                      // phase-B vocab pair (v0, v0+1)

    // ---- persistent weights in registers ----
    float whh[4][32];                 // Whh[jg*4+jj][lk*32 + k]
    #pragma unroll
    for (int jj = 0; jj < 4; ++jj) {
        const float4* s4 = (const float4*)(Whh + (size_t)((jg << 2) + jj) * HID + (lk << 5));
        #pragma unroll
        for (int k4 = 0; k4 < 8; ++k4) {
            float4 f = s4[k4];
            whh[jj][4*k4+0] = f.x; whh[jj][4*k4+1] = f.y;
            whh[jj][4*k4+2] = f.z; whh[jj][4*k4+3] = f.w;
        }
    }
    float wy[2][32];                  // Why[v0+r][lk*32 + k]
    #pragma unroll
    for (int r = 0; r < 2; ++r) {
        const float4* s4 = (const float4*)(Why + (size_t)(v0 + r) * HID + (lk << 5));
        #pragma unroll
        for (int k4 = 0; k4 < 8; ++k4) {
            float4 f = s4[k4];
            wy[r][4*k4+0] = f.x; wy[r][4*k4+1] = f.y;
            wy[r][4*k4+2] = f.z; wy[r][4*k4+3] = f.w;
        }
    }

    // swizzled LDS byte offsets for this lane's k-slice (shared by phases A and B)
    int hoff[8];
    #pragma unroll
    for (int i = 0; i < 8; ++i) hoff[i] = (lk << 7) + ((i ^ lk) << 4);

    // h' store offset (floats, within parity): row + swizzled position of jsel
    int hwoff;
    {
        int c = jsel >> 2;
        hwoff = ((tid & 4) << 6) + ((swz_c(c) << 2) | (jsel & 3));
    }

    // ---- init h parity 0 (both rows = h0), swizzled ----
    {
        int row = tid >> 8, j = tid & 255;
        h_s[row * HID + ((swz_c(j >> 2) << 2) | (j & 3))] = h0[j];
    }

    // ---- x-path: u_x(t) = P[idx_t] + P[idx_0]; biases folded ----
    const size_t xb0 = (size_t)r0 * SEQ;
    const size_t xb1 = xb0 + SEQ;
    const int i00 = x[xb0];
    const int i01 = x[xb1];
    const int i0sel = rsel ? i01 : i00;
    const float pinit = g_P[(size_t)i0sel * HID + jsel];
    const float cst   = pinit + bhh[jsel] + bxh[jsel];  // P[idx_0] + b  (loop-invariant)
    float pt = pinit;                                    // P[idx_t], t=0
    int inx0 = x[xb0 + 1];                               // x[.][t+1] at top of step t
    int inx1 = x[xb1 + 1];

    // phase-B output pointer (valid for lk<4; advanced by VOCAB per step)
    const int orow = (lk >> 1) & 1;
    const int ov   = v0 + (lk & 1);
    float* outp = out + (size_t)(r0 + orow) * NSTEP * VOCAB + ov;
    const float bsel = bhy[ov];

    __syncthreads();

    for (int t = 0; t < NSTEP; ++t) {
        const int cur = t & 1, nxt = cur ^ 1;

        // prefetch P row for t+1 (addr ready since last step), refill idx for t+2
        const int isel = rsel ? inx1 : inx0;
        const float pn = g_P[(size_t)isel * HID + jsel];
        {
            int tt = t + 2; tt = (tt < SEQ) ? tt : (SEQ - 1);
            inx0 = x[xb0 + tt];
            inx1 = x[xb1 + tt];
        }

        // ============ phase A: u = Whh*h + P[idx_t] + P[idx_0] + b ; h' = tanh(u)
        const char* hpar = (const char*)h_s + (cur << 11);
        float a0[4] = {0,0,0,0};   // row 0 partials, j = jg*4 + jj
        float a1[4] = {0,0,0,0};   // row 1
        #pragma unroll
        for (int i = 0; i < 8; ++i) {
            float4 h0v = *(const float4*)(hpar + hoff[i]);
            float4 h1v = *(const float4*)(hpar + 1024 + hoff[i]);
            #pragma unroll
            for (int jj = 0; jj < 4; ++jj) {
                a0[jj] += whh[jj][4*i+0]*h0v.x + whh[jj][4*i+1]*h0v.y
                        + whh[jj][4*i+2]*h0v.z + whh[jj][4*i+3]*h0v.w;
                a1[jj] += whh[jj][4*i+0]*h1v.x + whh[jj][4*i+1]*h1v.y
                        + whh[jj][4*i+2]*h1v.z + whh[jj][4*i+3]*h1v.w;
            }
        }
        // reduce-scatter over the 8-lane lk group; lane ends with j = jg*4+(tid&3)
        // (send the partial the PARTNER keeps; shfl_xor returns partner's copy)
        float u0, u1;
        {
            float k0 = (lk & 1) ? a0[1] : a0[0];
            float s0 = (lk & 1) ? a0[0] : a0[1];
            k0 += __shfl_xor(s0, 1);
            float k1 = (lk & 1) ? a0[3] : a0[2];
            float s1 = (lk & 1) ? a0[2] : a0[3];
            k1 += __shfl_xor(s1, 1);
            float ka = (lk & 2) ? k1 : k0;
            float sa = (lk & 2) ? k0 : k1;
            ka += __shfl_xor(sa, 2);
            ka += __shfl_xor(ka, 4);
            u0 = ka;
        }
        {
            float k0 = (lk & 1) ? a1[1] : a1[0];
            float s0 = (lk & 1) ? a1[0] : a1[1];
            k0 += __shfl_xor(s0, 1);
            float k1 = (lk & 1) ? a1[3] : a1[2];
            float s1 = (lk & 1) ? a1[2] : a1[3];
            k1 += __shfl_xor(s1, 1);
            float ka = (lk & 2) ? k1 : k0;
            float sa = (lk & 2) ? k0 : k1;
            ka += __shfl_xor(sa, 2);
            ka += __shfl_xor(ka, 4);
            u1 = ka;
        }
        // this lane finalizes its row only: tanh(u) = 1 - 2/(exp(2u)+1)  (inf-safe)
        {
            float u = (rsel ? u1 : u0) + cst + pt;
            float e = __expf(2.0f * u);
            float hn = 1.0f - 2.0f / (e + 1.0f);
            h_s[(nxt << 9) + hwoff] = hn;
        }
        pt = pn;

        __syncthreads();   // sole barrier: h'(t+1) visible to all

        // ============ phase B: y_t = h' * Why^T + bhy
        {
            const char* hp = (const char*)h_s + (nxt << 11);
            float b00 = 0.f, b10 = 0.f, b01 = 0.f, b11 = 0.f;  // [v-lane][batch-row]
            #pragma unroll
            for (int i = 0; i < 8; ++i) {
                float4 h0v = *(const float4*)(hp + hoff[i]);
                float4 h1v = *(const float4*)(hp + 1024 + hoff[i]);
                b00 += wy[0][4*i+0]*h0v.x + wy[0][4*i+1]*h0v.y
                     + wy[0][4*i+2]*h0v.z + wy[0][4*i+3]*h0v.w;
                b10 += wy[1][4*i+0]*h0v.x + wy[1][4*i+1]*h0v.y
                     + wy[1][4*i+2]*h0v.z + wy[1][4*i+3]*h0v.w;
                b01 += wy[0][4*i+0]*h1v.x + wy[0][4*i+1]*h1v.y
                     + wy[0][4*i+2]*h1v.z + wy[0][4*i+3]*h1v.w;
                b11 += wy[1][4*i+0]*h1v.x + wy[1][4*i+1]*h1v.y
                     + wy[1][4*i+2]*h1v.z + wy[1][4*i+3]*h1v.w;
            }
            // reduce-scatter over lk group: lane lk<4 owns (v0+(lk&1), row lk>>1)
            float kr0 = (lk & 1) ? b10 : b00;
            float sr0 = (lk & 1) ? b00 : b10;
            kr0 += __shfl_xor(sr0, 1);
            float kr1 = (lk & 1) ? b11 : b01;
            float sr1 = (lk & 1) ? b01 : b11;
            kr1 += __shfl_xor(sr1, 1);
            float kv = (lk & 2) ? kr1 : kr0;
            float sv = (lk & 2) ? kr0 : kr1;
            kv += __shfl_xor(sv, 2);
            kv += __shfl_xor(kv, 4);
            if (lk < 4) *outp = kv + bsel;
            outp += VOCAB;
        }
    }
}

extern "C" void kernel_launch(void* const* d_in, const int* in_sizes, int n_in,
                              void* d_out, int out_size, void* d_ws, size_t ws_size,
                              hipStream_t stream)
{
    (void)in_sizes; (void)n_in; (void)d_ws; (void)out_size;
    const int*   x   = (const int*)  d_in[0];
    const float* emb = (const float*)d_in[1];
    const float* Whh = (const float*)d_in[2];
    const float* bhh = (const float*)d_in[3];
    const float* Wxh = (const float*)d_in[4];
    const float* bxh = (const float*)d_in[5];
    const float* Why = (const float*)d_in[6];
    const float* bhy = (const float*)d_in[7];
    const float* h0  = (const float*)d_in[8];
    float* out = (float*)d_out;

    precompute_P<<<VOCAB, 256, 0, stream>>>(emb, Wxh);

    const size_t needH  = (size_t)512 * 511 * 256 * 4;   // 268 MB (fp32 H matrix)
    const size_t needHU = 2 * needH;                     // 536 MB
    if (ws_size >= needHU) {
        rnn_fused3<2><<<NBLK, BLK, 0, stream>>>(x, Whh, bhh, bxh, Why, bhy, h0, out);
    } else if (ws_size >= needH) {
        rnn_fused3<1><<<NBLK, BLK, 0, stream>>>(x, Whh, bhh, bxh, Why, bhy, h0, out);
    } else {
        rnn_fused3<0><<<NBLK, BLK, 0, stream>>>(x, Whh, bhh, bxh, Why, bhy, h0, out);
    }
}